// Round 2
// baseline (236.184 us; speedup 1.0000x reference)
//
#include <hip/hip_runtime.h>
#include <hip/hip_bf16.h>

typedef __attribute__((ext_vector_type(8))) short short8;
typedef __attribute__((ext_vector_type(4))) float f32x4;
typedef unsigned short ushort_t;
typedef unsigned int uint_t;

#define D_MODEL 512
#define D_ATTN  64
#define QKV_BLOCKS  1024   // 8 rows each -> 8192 rows
#define BIAS_BLOCKS 2048   // 4 rows each -> 8192 rows

__device__ __forceinline__ ushort_t f2bf(float f) {
    // round-to-nearest-even bf16 (finite inputs)
    uint_t u = __float_as_uint(f);
    u += 0x7FFFu + ((u >> 16) & 1u);
    return (ushort_t)(u >> 16);
}
__device__ __forceinline__ float bf2f(ushort_t h) {
    return __uint_as_float((uint_t)h << 16);
}

// ---------------- Kernel 1: fused top-stream (bias) + QKV projection ----------------
// blockIdx < QKV_BLOCKS: qkv blocks (start first, finish in ~15us, latency hidden
// under the 537MB top stream). Else: bias blocks streaming top at HBM rate.
__global__ __launch_bounds__(256)
void fused_stage1(const float* __restrict__ x, const float* __restrict__ top,
                  const float* __restrict__ Wq, const float* __restrict__ bq,
                  const float* __restrict__ Wk, const float* __restrict__ bk,
                  const float* __restrict__ Wv, const float* __restrict__ bv,
                  const float* __restrict__ Wt,
                  ushort_t* __restrict__ Q, ushort_t* __restrict__ K,
                  ushort_t* __restrict__ Vt, ushort_t* __restrict__ bias)
{
    const int tid = threadIdx.x;
    if (blockIdx.x < QKV_BLOCKS) {
        // ---- QKV path: 8 rows, wave 0->Q, 1->K, 2->V, 3 exits ----
        const int wv = tid >> 6;
        if (wv == 3) return;
        const int lane = tid & 63;
        const size_t row0 = (size_t)blockIdx.x * 8;
        const float* xb = x + row0 * D_MODEL;
        // pin pointer into VGPRs -> vector (broadcast) loads, not s_load:
        { uintptr_t u = (uintptr_t)xb; asm volatile("" : "+v"(u)); xb = (const float*)u; }
        const float* __restrict__ W = (wv == 0) ? Wq : ((wv == 1) ? Wk : Wv);

        float acc[8];
#pragma unroll
        for (int r = 0; r < 8; ++r) acc[r] = 0.0f;

#pragma unroll 2
        for (int k = 0; k < D_MODEL; k += 4) {
            float w0 = W[(k + 0) * D_ATTN + lane];
            float w1 = W[(k + 1) * D_ATTN + lane];
            float w2 = W[(k + 2) * D_ATTN + lane];
            float w3 = W[(k + 3) * D_ATTN + lane];
            float4 xr[8];
#pragma unroll
            for (int r = 0; r < 8; ++r)
                xr[r] = *(const float4*)(xb + r * D_MODEL + k);
#pragma unroll
            for (int r = 0; r < 8; ++r) {
                acc[r] = fmaf(xr[r].x, w0, acc[r]);
                acc[r] = fmaf(xr[r].y, w1, acc[r]);
                acc[r] = fmaf(xr[r].z, w2, acc[r]);
                acc[r] = fmaf(xr[r].w, w3, acc[r]);
            }
        }

        if (wv == 0) {
            float b0 = bq[lane];
#pragma unroll
            for (int r = 0; r < 8; ++r)
                Q[(row0 + r) * D_ATTN + lane] = f2bf((acc[r] + b0) * 0.125f); // fold 1/sqrt(64)
        } else if (wv == 1) {
            float b0 = bk[lane];
#pragma unroll
            for (int r = 0; r < 8; ++r)
                K[(row0 + r) * D_ATTN + lane] = f2bf(acc[r] + b0);
        } else {
            float b0 = bv[lane];
            uint_t pk[4];
#pragma unroll
            for (int r = 0; r < 8; r += 2)
                pk[r >> 1] = (uint_t)f2bf(acc[r] + b0) |
                             ((uint_t)f2bf(acc[r + 1] + b0) << 16);
            const int bb = (int)(row0 >> 10);
            const int n0 = (int)(row0 & 1023);
            // V transposed: Vt[b][d][n], 8 consecutive n per lane -> one 16B store
            *(uint4*)(Vt + ((size_t)bb * 64 + lane) * 1024 + n0) =
                make_uint4(pk[0], pk[1], pk[2], pk[3]);
        }
    } else {
        // ---- Bias path: 4 rows; bias[g][m] = top[g][m][:] . Wt  (bf16 out) ----
        const size_t g0 = (size_t)(blockIdx.x - QKV_BLOCKS) * 4;   // global row
        const float* __restrict__ topb = top + (g0 << 14);
        float wt[16];
#pragma unroll
        for (int i = 0; i < 16; ++i) wt[i] = Wt[i];
        uint_t* __restrict__ ob = (uint_t*)(bias + (g0 << 10));

#pragma unroll 2
        for (int it = 0; it < 8; ++it) {
            int r = it >> 1;
            int m = ((it & 1) << 9) + (tid << 1);   // even m; this thread does m, m+1
            const float4* tp = (const float4*)(topb + ((size_t)r << 14) + ((size_t)m << 4));
            float4 a0 = tp[0], a1 = tp[1], a2 = tp[2], a3 = tp[3];
            float4 c0 = tp[4], c1 = tp[5], c2 = tp[6], c3 = tp[7];
            float s0 = a0.x * wt[0];
            s0 = fmaf(a0.y, wt[1],  s0); s0 = fmaf(a0.z, wt[2],  s0); s0 = fmaf(a0.w, wt[3],  s0);
            s0 = fmaf(a1.x, wt[4],  s0); s0 = fmaf(a1.y, wt[5],  s0); s0 = fmaf(a1.z, wt[6],  s0);
            s0 = fmaf(a1.w, wt[7],  s0); s0 = fmaf(a2.x, wt[8],  s0); s0 = fmaf(a2.y, wt[9],  s0);
            s0 = fmaf(a2.z, wt[10], s0); s0 = fmaf(a2.w, wt[11], s0); s0 = fmaf(a3.x, wt[12], s0);
            s0 = fmaf(a3.y, wt[13], s0); s0 = fmaf(a3.z, wt[14], s0); s0 = fmaf(a3.w, wt[15], s0);
            float s1 = c0.x * wt[0];
            s1 = fmaf(c0.y, wt[1],  s1); s1 = fmaf(c0.z, wt[2],  s1); s1 = fmaf(c0.w, wt[3],  s1);
            s1 = fmaf(c1.x, wt[4],  s1); s1 = fmaf(c1.y, wt[5],  s1); s1 = fmaf(c1.z, wt[6],  s1);
            s1 = fmaf(c1.w, wt[7],  s1); s1 = fmaf(c2.x, wt[8],  s1); s1 = fmaf(c2.y, wt[9],  s1);
            s1 = fmaf(c2.z, wt[10], s1); s1 = fmaf(c2.w, wt[11], s1); s1 = fmaf(c3.x, wt[12], s1);
            s1 = fmaf(c3.y, wt[13], s1); s1 = fmaf(c3.z, wt[14], s1); s1 = fmaf(c3.w, wt[15], s1);
            ob[(r << 9) + (m >> 1)] = (uint_t)f2bf(s0) | ((uint_t)f2bf(s1) << 16);
            // bt dropped: softmax shift-invariant
        }
    }
}

// ---------------- Kernel 2: attention from precomputed bias ----------------
// grid 512 blocks (b * 64 row-tiles) x 256 threads (4 waves). LDS 64KB as before.
__global__ __launch_bounds__(256)
void topo_attn(const ushort_t* __restrict__ bias,
               const ushort_t* __restrict__ Q, const ushort_t* __restrict__ K,
               const ushort_t* __restrict__ Vt, float* __restrict__ out)
{
    __shared__ float lds[16384];
    const int tid = threadIdx.x;
    const int b   = blockIdx.x >> 6;
    const int bn0 = blockIdx.x << 4;   // b*1024 + n0

    // ---- Phase A': bias bf16 -> LDS logits f32 ----
    const ushort_t* __restrict__ bb = bias + ((size_t)bn0 << 10);
#pragma unroll
    for (int it = 0; it < 8; ++it) {
        int e0 = (it << 11) + (tid << 3);
        short8 v = *(const short8*)(bb + e0);
        f32x4 f0, f1;
#pragma unroll
        for (int j = 0; j < 4; ++j) f0[j] = bf2f((ushort_t)v[j]);
#pragma unroll
        for (int j = 0; j < 4; ++j) f1[j] = bf2f((ushort_t)v[4 + j]);
        *(f32x4*)(lds + e0)     = f0;
        *(f32x4*)(lds + e0 + 4) = f1;
    }
    __syncthreads();

    // ---- Phase B: logits += (Q/8) K^T via MFMA ----
    const int l = tid & 63, wv = tid >> 6;
    const int lr = l & 15, lg = l >> 4;
    const short8 a0 = *(const short8*)(Q + ((size_t)(bn0 + lr)) * 64 + 8 * lg);
    const short8 a1 = *(const short8*)(Q + ((size_t)(bn0 + lr)) * 64 + 32 + 8 * lg);
    const ushort_t* __restrict__ Kb = K + ((size_t)b << 16);
#pragma unroll 4
    for (int t16 = 0; t16 < 16; ++t16) {
        int m0 = (wv << 8) + (t16 << 4);
        short8 kb0 = *(const short8*)(Kb + (size_t)(m0 + lr) * 64 + 8 * lg);
        short8 kb1 = *(const short8*)(Kb + (size_t)(m0 + lr) * 64 + 32 + 8 * lg);
        f32x4 acc = {0.f, 0.f, 0.f, 0.f};
        acc = __builtin_amdgcn_mfma_f32_16x16x32_bf16(a0, kb0, acc, 0, 0, 0);
        acc = __builtin_amdgcn_mfma_f32_16x16x32_bf16(a1, kb1, acc, 0, 0, 0);
#pragma unroll
        for (int j = 0; j < 4; ++j)
            lds[(4 * lg + j) * 1024 + m0 + lr] += acc[j];  // C/D: col=lane&15, row=4*(l>>4)+j
    }
    __syncthreads();

    // ---- Phase C: row softmax; write P (bf16) aliased over logits[0:32KB) ----
    {
        const int r = tid >> 4, sseg = tid & 15;
        float4 v4[16];
        const float4* rowp = (const float4*)(lds + r * 1024 + sseg * 64);
#pragma unroll
        for (int i = 0; i < 16; ++i) v4[i] = rowp[i];
        __syncthreads();   // everyone finished reading logits before alias overwrite
        float mx = v4[0].x;
#pragma unroll
        for (int i = 0; i < 16; ++i)
            mx = fmaxf(mx, fmaxf(fmaxf(v4[i].x, v4[i].y), fmaxf(v4[i].z, v4[i].w)));
#pragma unroll
        for (int off = 8; off >= 1; off >>= 1) mx = fmaxf(mx, __shfl_xor(mx, off));
        float sum = 0.f;
#pragma unroll
        for (int i = 0; i < 16; ++i) {
            v4[i].x = __expf(v4[i].x - mx); sum += v4[i].x;
            v4[i].y = __expf(v4[i].y - mx); sum += v4[i].y;
            v4[i].z = __expf(v4[i].z - mx); sum += v4[i].z;
            v4[i].w = __expf(v4[i].w - mx); sum += v4[i].w;
        }
#pragma unroll
        for (int off = 8; off >= 1; off >>= 1) sum += __shfl_xor(sum, off);
        float inv = 1.0f / sum;
        ushort_t* pb = ((ushort_t*)lds) + r * 1024 + sseg * 64;
#pragma unroll
        for (int i = 0; i < 8; ++i) {
            uint_t w0 = (uint_t)f2bf(v4[2*i].x * inv)   | ((uint_t)f2bf(v4[2*i].y * inv)   << 16);
            uint_t w1 = (uint_t)f2bf(v4[2*i].z * inv)   | ((uint_t)f2bf(v4[2*i].w * inv)   << 16);
            uint_t w2 = (uint_t)f2bf(v4[2*i+1].x * inv) | ((uint_t)f2bf(v4[2*i+1].y * inv) << 16);
            uint_t w3 = (uint_t)f2bf(v4[2*i+1].z * inv) | ((uint_t)f2bf(v4[2*i+1].w * inv) << 16);
            ((uint4*)pb)[i] = make_uint4(w0, w1, w2, w3);
        }
    }
    __syncthreads();

    // ---- Phase D: out = P V  (V transposed -> contiguous B-frag loads) ----
    {
        f32x4 o[4] = {{0,0,0,0},{0,0,0,0},{0,0,0,0},{0,0,0,0}};
        const ushort_t* __restrict__ pb = ((const ushort_t*)lds) + lr * 1024;
        const ushort_t* __restrict__ Vb = Vt + ((size_t)b << 16);
#pragma unroll 2
        for (int c = 0; c < 8; ++c) {
            int m0 = (wv << 8) + (c << 5) + 8 * lg;
            short8 pa = *(const short8*)(pb + m0);
#pragma unroll
            for (int dt = 0; dt < 4; ++dt) {
                short8 vb = *(const short8*)(Vb + (size_t)(dt * 16 + lr) * 1024 + m0);
                o[dt] = __builtin_amdgcn_mfma_f32_16x16x32_bf16(pa, vb, o[dt], 0, 0, 0);
            }
        }
        float* lo = lds + 8192 + (wv << 10);   // partial out, disjoint from P
#pragma unroll
        for (int dt = 0; dt < 4; ++dt)
#pragma unroll
            for (int j = 0; j < 4; ++j)
                lo[(4 * lg + j) * 64 + dt * 16 + lr] = o[dt][j];
    }
    __syncthreads();

    // ---- cross-wave reduce + coalesced store ----
#pragma unroll
    for (int i = 0; i < 4; ++i) {
        int idx = (i << 8) + tid;   // r*64 + d
        float s2 = lds[8192 + idx] + lds[8192 + 1024 + idx]
                 + lds[8192 + 2048 + idx] + lds[8192 + 3072 + idx];
        out[((size_t)bn0 << 6) + idx] = s2;
    }
}

extern "C" void kernel_launch(void* const* d_in, const int* in_sizes, int n_in,
                              void* d_out, int out_size, void* d_ws, size_t ws_size,
                              hipStream_t stream) {
    const float* x   = (const float*)d_in[0];
    const float* top = (const float*)d_in[1];
    const float* Wq  = (const float*)d_in[2];
    const float* bq  = (const float*)d_in[3];
    const float* Wk  = (const float*)d_in[4];
    const float* bk  = (const float*)d_in[5];
    const float* Wv  = (const float*)d_in[6];
    const float* bv  = (const float*)d_in[7];
    const float* Wt  = (const float*)d_in[8];
    // d_in[9] = bt: constant added to every logit -> softmax-invariant, dropped.
    float* out = (float*)d_out;

    ushort_t* Q    = (ushort_t*)d_ws;            // [8][1024][64] bf16 (pre-scaled 1/8)
    ushort_t* K    = Q + 8 * 1024 * 64;          // [8][1024][64] bf16
    ushort_t* Vt   = K + 8 * 1024 * 64;          // [8][64][1024] bf16 (transposed)
    ushort_t* bias = Vt + 8 * 1024 * 64;         // [8][1024][1024] bf16

    fused_stage1<<<QKV_BLOCKS + BIAS_BLOCKS, 256, 0, stream>>>(
        x, top, Wq, bq, Wk, bk, Wv, bv, Wt, Q, K, Vt, bias);
    topo_attn<<<512, 256, 0, stream>>>(bias, Q, K, Vt, out);
}

// Round 3
// 210.104 us; speedup vs baseline: 1.1241x; 1.1241x over previous
//
#include <hip/hip_runtime.h>
#include <hip/hip_bf16.h>

typedef __attribute__((ext_vector_type(8))) short short8;
typedef __attribute__((ext_vector_type(4))) float f32x4;
typedef unsigned short ushort_t;
typedef unsigned int uint_t;

#define D_MODEL 512
#define D_ATTN  64
#define QKV_BLOCKS  1024   // 8 rows each -> 8192 rows
#define BIAS_BLOCKS 2048   // 4 bias rows each (1 per wave) -> 8192 rows

__device__ __forceinline__ ushort_t f2bf(float f) {
    // round-to-nearest-even bf16 (finite inputs)
    uint_t u = __float_as_uint(f);
    u += 0x7FFFu + ((u >> 16) & 1u);
    return (ushort_t)(u >> 16);
}
__device__ __forceinline__ float bf2f(ushort_t h) {
    return __uint_as_float((uint_t)h << 16);
}

// ---------------- Kernel 1: fused top-stream (bias) + QKV projection ----------------
// blockIdx < QKV_BLOCKS: qkv blocks (latency hidden under the 537MB top stream).
// Else: bias blocks streaming top with LANE-CONTIGUOUS float4 loads (8 cache
// lines per instruction) + 4-lane shfl_xor dot-reduce.
__global__ __launch_bounds__(256)
void fused_stage1(const float* __restrict__ x, const float* __restrict__ top,
                  const float* __restrict__ Wq, const float* __restrict__ bq,
                  const float* __restrict__ Wk, const float* __restrict__ bk,
                  const float* __restrict__ Wv, const float* __restrict__ bv,
                  const float* __restrict__ Wt,
                  ushort_t* __restrict__ Q, ushort_t* __restrict__ K,
                  ushort_t* __restrict__ Vt, ushort_t* __restrict__ bias)
{
    __shared__ float ldsb[4096];   // 4 waves x 1024 f32 bias row
    const int tid = threadIdx.x;
    if (blockIdx.x < QKV_BLOCKS) {
        // ---- QKV path: 8 rows, wave 0->Q, 1->K, 2->V, 3 exits ----
        const int wv = tid >> 6;
        if (wv == 3) return;
        const int lane = tid & 63;
        const size_t row0 = (size_t)blockIdx.x * 8;
        const float* xb = x + row0 * D_MODEL;
        // pin pointer into VGPRs -> vector (broadcast) loads, not s_load:
        { uintptr_t u = (uintptr_t)xb; asm volatile("" : "+v"(u)); xb = (const float*)u; }
        const float* __restrict__ W = (wv == 0) ? Wq : ((wv == 1) ? Wk : Wv);

        float acc[8];
#pragma unroll
        for (int r = 0; r < 8; ++r) acc[r] = 0.0f;

#pragma unroll 2
        for (int k = 0; k < D_MODEL; k += 4) {
            float w0 = W[(k + 0) * D_ATTN + lane];
            float w1 = W[(k + 1) * D_ATTN + lane];
            float w2 = W[(k + 2) * D_ATTN + lane];
            float w3 = W[(k + 3) * D_ATTN + lane];
            float4 xr[8];
#pragma unroll
            for (int r = 0; r < 8; ++r)
                xr[r] = *(const float4*)(xb + r * D_MODEL + k);
#pragma unroll
            for (int r = 0; r < 8; ++r) {
                acc[r] = fmaf(xr[r].x, w0, acc[r]);
                acc[r] = fmaf(xr[r].y, w1, acc[r]);
                acc[r] = fmaf(xr[r].z, w2, acc[r]);
                acc[r] = fmaf(xr[r].w, w3, acc[r]);
            }
        }

        if (wv == 0) {
            float b0 = bq[lane];
#pragma unroll
            for (int r = 0; r < 8; ++r)
                Q[(row0 + r) * D_ATTN + lane] = f2bf((acc[r] + b0) * 0.125f); // fold 1/sqrt(64)
        } else if (wv == 1) {
            float b0 = bk[lane];
#pragma unroll
            for (int r = 0; r < 8; ++r)
                K[(row0 + r) * D_ATTN + lane] = f2bf(acc[r] + b0);
        } else {
            float b0 = bv[lane];
            uint_t pk[4];
#pragma unroll
            for (int r = 0; r < 8; r += 2)
                pk[r >> 1] = (uint_t)f2bf(acc[r] + b0) |
                             ((uint_t)f2bf(acc[r + 1] + b0) << 16);
            const int bb = (int)(row0 >> 10);
            const int n0 = (int)(row0 & 1023);
            // V transposed: Vt[b][d][n]
            *(uint4*)(Vt + ((size_t)bb * 64 + lane) * 1024 + n0) =
                make_uint4(pk[0], pk[1], pk[2], pk[3]);
        }
    } else {
        // ---- Bias path: 1 row per wave; lane-contiguous loads + xor-reduce ----
        const int l = tid & 63, w = tid >> 6;
        const size_t row = (((size_t)blockIdx.x - QKV_BLOCKS) << 2) + w;  // 0..8191
        const float* __restrict__ rp = top + (row << 14);   // 1024*16 floats
        uint_t* __restrict__ op = (uint_t*)(bias + (row << 10));
        const float4 wq = *(const float4*)(Wt + ((l & 3) << 2));  // my quarter of Wt
        float* __restrict__ ldsrow = ldsb + (w << 10);

        // 16 groups; each group = 64 outputs = 4KB input, 4 coalesced loads
#pragma unroll 2
        for (int g = 0; g < 16; ++g) {
            const float4* gp = (const float4*)(rp + ((size_t)g << 10));
            float4 v0 = gp[l];
            float4 v1 = gp[64 + l];
            float4 v2 = gp[128 + l];
            float4 v3 = gp[192 + l];
            float p0 = v0.x * wq.x; p0 = fmaf(v0.y, wq.y, p0); p0 = fmaf(v0.z, wq.z, p0); p0 = fmaf(v0.w, wq.w, p0);
            float p1 = v1.x * wq.x; p1 = fmaf(v1.y, wq.y, p1); p1 = fmaf(v1.z, wq.z, p1); p1 = fmaf(v1.w, wq.w, p1);
            float p2 = v2.x * wq.x; p2 = fmaf(v2.y, wq.y, p2); p2 = fmaf(v2.z, wq.z, p2); p2 = fmaf(v2.w, wq.w, p2);
            float p3 = v3.x * wq.x; p3 = fmaf(v3.y, wq.y, p3); p3 = fmaf(v3.z, wq.z, p3); p3 = fmaf(v3.w, wq.w, p3);
            // fold quarters across 4-lane group
            p0 += __shfl_xor(p0, 1); p0 += __shfl_xor(p0, 2);
            p1 += __shfl_xor(p1, 1); p1 += __shfl_xor(p1, 2);
            p2 += __shfl_xor(p2, 1); p2 += __shfl_xor(p2, 2);
            p3 += __shfl_xor(p3, 1); p3 += __shfl_xor(p3, 2);
            if ((l & 3) == 0) {
                int mb = (g << 6) + (l >> 2);   // output m within row
                ldsrow[mb]      = p0;           // banks: 16 distinct, conflict-free
                ldsrow[mb + 16] = p1;
                ldsrow[mb + 32] = p2;
                ldsrow[mb + 48] = p3;
            }
        }
        // pack row to bf16, coalesced 256B stores (bt dropped: shift-invariant)
#pragma unroll
        for (int c = 0; c < 8; ++c) {
            float2 t = *(const float2*)(ldsrow + (c << 7) + (l << 1));
            op[(c << 6) + l] = (uint_t)f2bf(t.x) | ((uint_t)f2bf(t.y) << 16);
        }
    }
}

// ---------------- Kernel 2: attention from precomputed bias ----------------
// grid 512 blocks (b * 64 row-tiles) x 256 threads (4 waves). LDS 64KB as before.
__global__ __launch_bounds__(256)
void topo_attn(const ushort_t* __restrict__ bias,
               const ushort_t* __restrict__ Q, const ushort_t* __restrict__ K,
               const ushort_t* __restrict__ Vt, float* __restrict__ out)
{
    __shared__ float lds[16384];
    const int tid = threadIdx.x;
    const int b   = blockIdx.x >> 6;
    const int bn0 = blockIdx.x << 4;   // b*1024 + n0

    // ---- Phase A': bias bf16 -> LDS logits f32 ----
    const ushort_t* __restrict__ bb = bias + ((size_t)bn0 << 10);
#pragma unroll
    for (int it = 0; it < 8; ++it) {
        int e0 = (it << 11) + (tid << 3);
        short8 v = *(const short8*)(bb + e0);
        f32x4 f0, f1;
#pragma unroll
        for (int j = 0; j < 4; ++j) f0[j] = bf2f((ushort_t)v[j]);
#pragma unroll
        for (int j = 0; j < 4; ++j) f1[j] = bf2f((ushort_t)v[4 + j]);
        *(f32x4*)(lds + e0)     = f0;
        *(f32x4*)(lds + e0 + 4) = f1;
    }
    __syncthreads();

    // ---- Phase B: logits += (Q/8) K^T via MFMA ----
    const int l = tid & 63, wv = tid >> 6;
    const int lr = l & 15, lg = l >> 4;
    const short8 a0 = *(const short8*)(Q + ((size_t)(bn0 + lr)) * 64 + 8 * lg);
    const short8 a1 = *(const short8*)(Q + ((size_t)(bn0 + lr)) * 64 + 32 + 8 * lg);
    const ushort_t* __restrict__ Kb = K + ((size_t)b << 16);
#pragma unroll 4
    for (int t16 = 0; t16 < 16; ++t16) {
        int m0 = (wv << 8) + (t16 << 4);
        short8 kb0 = *(const short8*)(Kb + (size_t)(m0 + lr) * 64 + 8 * lg);
        short8 kb1 = *(const short8*)(Kb + (size_t)(m0 + lr) * 64 + 32 + 8 * lg);
        f32x4 acc = {0.f, 0.f, 0.f, 0.f};
        acc = __builtin_amdgcn_mfma_f32_16x16x32_bf16(a0, kb0, acc, 0, 0, 0);
        acc = __builtin_amdgcn_mfma_f32_16x16x32_bf16(a1, kb1, acc, 0, 0, 0);
#pragma unroll
        for (int j = 0; j < 4; ++j)
            lds[(4 * lg + j) * 1024 + m0 + lr] += acc[j];  // C/D: col=lane&15, row=4*(l>>4)+j
    }
    __syncthreads();

    // ---- Phase C: row softmax; write P (bf16) aliased over logits[0:32KB) ----
    {
        const int r = tid >> 4, sseg = tid & 15;
        float4 v4[16];
        const float4* rowp = (const float4*)(lds + r * 1024 + sseg * 64);
#pragma unroll
        for (int i = 0; i < 16; ++i) v4[i] = rowp[i];
        __syncthreads();   // everyone finished reading logits before alias overwrite
        float mx = v4[0].x;
#pragma unroll
        for (int i = 0; i < 16; ++i)
            mx = fmaxf(mx, fmaxf(fmaxf(v4[i].x, v4[i].y), fmaxf(v4[i].z, v4[i].w)));
#pragma unroll
        for (int off = 8; off >= 1; off >>= 1) mx = fmaxf(mx, __shfl_xor(mx, off));
        float sum = 0.f;
#pragma unroll
        for (int i = 0; i < 16; ++i) {
            v4[i].x = __expf(v4[i].x - mx); sum += v4[i].x;
            v4[i].y = __expf(v4[i].y - mx); sum += v4[i].y;
            v4[i].z = __expf(v4[i].z - mx); sum += v4[i].z;
            v4[i].w = __expf(v4[i].w - mx); sum += v4[i].w;
        }
#pragma unroll
        for (int off = 8; off >= 1; off >>= 1) sum += __shfl_xor(sum, off);
        float inv = 1.0f / sum;
        ushort_t* pb = ((ushort_t*)lds) + r * 1024 + sseg * 64;
#pragma unroll
        for (int i = 0; i < 8; ++i) {
            uint_t w0 = (uint_t)f2bf(v4[2*i].x * inv)   | ((uint_t)f2bf(v4[2*i].y * inv)   << 16);
            uint_t w1 = (uint_t)f2bf(v4[2*i].z * inv)   | ((uint_t)f2bf(v4[2*i].w * inv)   << 16);
            uint_t w2 = (uint_t)f2bf(v4[2*i+1].x * inv) | ((uint_t)f2bf(v4[2*i+1].y * inv) << 16);
            uint_t w3 = (uint_t)f2bf(v4[2*i+1].z * inv) | ((uint_t)f2bf(v4[2*i+1].w * inv) << 16);
            ((uint4*)pb)[i] = make_uint4(w0, w1, w2, w3);
        }
    }
    __syncthreads();

    // ---- Phase D: out = P V  (V transposed -> contiguous B-frag loads) ----
    {
        f32x4 o[4] = {{0,0,0,0},{0,0,0,0},{0,0,0,0},{0,0,0,0}};
        const ushort_t* __restrict__ pb = ((const ushort_t*)lds) + lr * 1024;
        const ushort_t* __restrict__ Vb = Vt + ((size_t)b << 16);
#pragma unroll 2
        for (int c = 0; c < 8; ++c) {
            int m0 = (wv << 8) + (c << 5) + 8 * lg;
            short8 pa = *(const short8*)(pb + m0);
#pragma unroll
            for (int dt = 0; dt < 4; ++dt) {
                short8 vb = *(const short8*)(Vb + (size_t)(dt * 16 + lr) * 1024 + m0);
                o[dt] = __builtin_amdgcn_mfma_f32_16x16x32_bf16(pa, vb, o[dt], 0, 0, 0);
            }
        }
        float* lo = lds + 8192 + (wv << 10);   // partial out, disjoint from P
#pragma unroll
        for (int dt = 0; dt < 4; ++dt)
#pragma unroll
            for (int j = 0; j < 4; ++j)
                lo[(4 * lg + j) * 64 + dt * 16 + lr] = o[dt][j];
    }
    __syncthreads();

    // ---- cross-wave reduce + coalesced store ----
#pragma unroll
    for (int i = 0; i < 4; ++i) {
        int idx = (i << 8) + tid;   // r*64 + d
        float s2 = lds[8192 + idx] + lds[8192 + 1024 + idx]
                 + lds[8192 + 2048 + idx] + lds[8192 + 3072 + idx];
        out[((size_t)bn0 << 6) + idx] = s2;
    }
}

extern "C" void kernel_launch(void* const* d_in, const int* in_sizes, int n_in,
                              void* d_out, int out_size, void* d_ws, size_t ws_size,
                              hipStream_t stream) {
    const float* x   = (const float*)d_in[0];
    const float* top = (const float*)d_in[1];
    const float* Wq  = (const float*)d_in[2];
    const float* bq  = (const float*)d_in[3];
    const float* Wk  = (const float*)d_in[4];
    const float* bk  = (const float*)d_in[5];
    const float* Wv  = (const float*)d_in[6];
    const float* bv  = (const float*)d_in[7];
    const float* Wt  = (const float*)d_in[8];
    // d_in[9] = bt: constant added to every logit -> softmax-invariant, dropped.
    float* out = (float*)d_out;

    ushort_t* Q    = (ushort_t*)d_ws;            // [8][1024][64] bf16 (pre-scaled 1/8)
    ushort_t* K    = Q + 8 * 1024 * 64;          // [8][1024][64] bf16
    ushort_t* Vt   = K + 8 * 1024 * 64;          // [8][64][1024] bf16 (transposed)
    ushort_t* bias = Vt + 8 * 1024 * 64;         // [8][1024][1024] bf16

    fused_stage1<<<QKV_BLOCKS + BIAS_BLOCKS, 256, 0, stream>>>(
        x, top, Wq, bq, Wk, bk, Wv, bv, Wt, Q, K, Vt, bias);
    topo_attn<<<512, 256, 0, stream>>>(bias, Q, K, Vt, out);
}

// Round 4
// 164.477 us; speedup vs baseline: 1.4360x; 1.2774x over previous
//
#include <hip/hip_runtime.h>
#include <hip/hip_bf16.h>

typedef __attribute__((ext_vector_type(8))) short short8;
typedef __attribute__((ext_vector_type(4))) float f32x4;
typedef unsigned short ushort_t;
typedef unsigned int uint_t;

#define D_MODEL 512
#define D_ATTN  64

__device__ __forceinline__ ushort_t f2bf(float f) {
    // round-to-nearest-even bf16 (finite inputs)
    uint_t u = __float_as_uint(f);
    u += 0x7FFFu + ((u >> 16) & 1u);
    return (ushort_t)(u >> 16);
}
__device__ __forceinline__ f32x4 ntload4(const f32x4* p) {
    return __builtin_nontemporal_load(p);   // top is read exactly once: stream hint
}

// ---------------- Kernel 1: QKV, all components per wave ----------------
// 512 blocks x 256 thr. Block = 16 rows; wave w -> rows 4w..4w+3, computes
// Q,K,V for them (x loaded once, shared by the three dot products).
__global__ __launch_bounds__(256)
void qkv_all(const float* __restrict__ x,
             const float* __restrict__ Wq, const float* __restrict__ bq,
             const float* __restrict__ Wk, const float* __restrict__ bk,
             const float* __restrict__ Wv, const float* __restrict__ bv,
             ushort_t* __restrict__ Q, ushort_t* __restrict__ K,
             ushort_t* __restrict__ Vt)
{
    const int l = threadIdx.x & 63, w = threadIdx.x >> 6;
    const size_t bn0 = (size_t)blockIdx.x << 4;
    const int r0 = w << 2;
    const float* xb = x + (bn0 + r0) * D_MODEL;
    { uintptr_t u = (uintptr_t)xb; asm volatile("" : "+v"(u)); xb = (const float*)u; }

    float aq[4] = {0,0,0,0}, ak[4] = {0,0,0,0}, av[4] = {0,0,0,0};
#pragma unroll 2
    for (int k = 0; k < D_MODEL; k += 4) {
        float4 xr[4];
#pragma unroll
        for (int r = 0; r < 4; ++r) xr[r] = *(const float4*)(xb + r * D_MODEL + k);
        float wqv[4], wkv[4], wvv[4];
#pragma unroll
        for (int kk = 0; kk < 4; ++kk) {
            wqv[kk] = Wq[(k + kk) * D_ATTN + l];
            wkv[kk] = Wk[(k + kk) * D_ATTN + l];
            wvv[kk] = Wv[(k + kk) * D_ATTN + l];
        }
#pragma unroll
        for (int r = 0; r < 4; ++r) {
            const float xv[4] = {xr[r].x, xr[r].y, xr[r].z, xr[r].w};
#pragma unroll
            for (int kk = 0; kk < 4; ++kk) {
                aq[r] = fmaf(xv[kk], wqv[kk], aq[r]);
                ak[r] = fmaf(xv[kk], wkv[kk], ak[r]);
                av[r] = fmaf(xv[kk], wvv[kk], av[r]);
            }
        }
    }
    const float bqv = bq[l], bkv = bk[l], bvv = bv[l];
#pragma unroll
    for (int r = 0; r < 4; ++r) {
        Q[(bn0 + r0 + r) * D_ATTN + l] = f2bf((aq[r] + bqv) * 0.125f); // fold 1/sqrt(64)
        K[(bn0 + r0 + r) * D_ATTN + l] = f2bf(ak[r] + bkv);
    }
    // Vt[b][d][n]: this block owns 16 consecutive n; this wave 4 of them.
    const int b = (int)(bn0 >> 10), n0loc = (int)(bn0 & 1023);
    uint2 pv;
    pv.x = (uint_t)f2bf(av[0] + bvv) | ((uint_t)f2bf(av[1] + bvv) << 16);
    pv.y = (uint_t)f2bf(av[2] + bvv) | ((uint_t)f2bf(av[3] + bvv) << 16);
    *(uint2*)(Vt + ((size_t)(b * 64 + l) << 10) + n0loc + r0) = pv;
}

// ---------------- Kernel 2: fused stream + attention ----------------
// 512 blocks (b*64 tiles) x 256 thr, 64KB LDS, 2 blocks/CU.
// Phase A: NT lane-contiguous stream of top (1MB/block) -> f32 logits in LDS.
__global__ __launch_bounds__(256)
void topo_attn_f(const float* __restrict__ top, const float* __restrict__ Wt,
                 const ushort_t* __restrict__ Q, const ushort_t* __restrict__ K,
                 const ushort_t* __restrict__ Vt, float* __restrict__ out)
{
    __shared__ float lds[16384];
    const int tid = threadIdx.x;
    const int l = tid & 63, wv = tid >> 6;
    const int b   = blockIdx.x >> 6;
    const int bn0 = blockIdx.x << 4;   // b*1024 + n0

    // ---- Phase A: bias[r][m] = top[bn0+r][m][:] . Wt  (the 537MB stream) ----
    {
        const float* __restrict__ topb = top + ((size_t)bn0 << 14);
        const float4 wq = *(const float4*)(Wt + ((l & 3) << 2));  // my Wt quarter
#pragma unroll
        for (int rr = 0; rr < 4; ++rr) {
            const int rloc = (wv << 2) + rr;
            const f32x4* gp = (const f32x4*)(topb + ((size_t)rloc << 14));
            float* ldsrow = lds + (rloc << 10);
#pragma unroll 2
            for (int g = 0; g < 16; ++g) {
                f32x4 v0 = ntload4(gp + (g << 8) + l);
                f32x4 v1 = ntload4(gp + (g << 8) + 64 + l);
                f32x4 v2 = ntload4(gp + (g << 8) + 128 + l);
                f32x4 v3 = ntload4(gp + (g << 8) + 192 + l);
                float p0 = v0[0] * wq.x; p0 = fmaf(v0[1], wq.y, p0); p0 = fmaf(v0[2], wq.z, p0); p0 = fmaf(v0[3], wq.w, p0);
                float p1 = v1[0] * wq.x; p1 = fmaf(v1[1], wq.y, p1); p1 = fmaf(v1[2], wq.z, p1); p1 = fmaf(v1[3], wq.w, p1);
                float p2 = v2[0] * wq.x; p2 = fmaf(v2[1], wq.y, p2); p2 = fmaf(v2[2], wq.z, p2); p2 = fmaf(v2[3], wq.w, p2);
                float p3 = v3[0] * wq.x; p3 = fmaf(v3[1], wq.y, p3); p3 = fmaf(v3[2], wq.z, p3); p3 = fmaf(v3[3], wq.w, p3);
                p0 += __shfl_xor(p0, 1); p0 += __shfl_xor(p0, 2);
                p1 += __shfl_xor(p1, 1); p1 += __shfl_xor(p1, 2);
                p2 += __shfl_xor(p2, 1); p2 += __shfl_xor(p2, 2);
                p3 += __shfl_xor(p3, 1); p3 += __shfl_xor(p3, 2);
                if (!(l & 3)) {
                    int mb = (g << 6) + (l >> 2);
                    ldsrow[mb]      = p0;   // 16 consecutive words: conflict-free
                    ldsrow[mb + 16] = p1;
                    ldsrow[mb + 32] = p2;
                    ldsrow[mb + 48] = p3;
                }
            }
        }
        // bt dropped: softmax shift-invariant
    }
    __syncthreads();

    // ---- Phase B: logits += (Q/8) K^T via MFMA ----
    const int lr = l & 15, lg = l >> 4;
    const short8 a0 = *(const short8*)(Q + ((size_t)(bn0 + lr)) * 64 + 8 * lg);
    const short8 a1 = *(const short8*)(Q + ((size_t)(bn0 + lr)) * 64 + 32 + 8 * lg);
    const ushort_t* __restrict__ Kb = K + ((size_t)b << 16);
#pragma unroll 4
    for (int t16 = 0; t16 < 16; ++t16) {
        int m0 = (wv << 8) + (t16 << 4);
        short8 kb0 = *(const short8*)(Kb + (size_t)(m0 + lr) * 64 + 8 * lg);
        short8 kb1 = *(const short8*)(Kb + (size_t)(m0 + lr) * 64 + 32 + 8 * lg);
        f32x4 acc = {0.f, 0.f, 0.f, 0.f};
        acc = __builtin_amdgcn_mfma_f32_16x16x32_bf16(a0, kb0, acc, 0, 0, 0);
        acc = __builtin_amdgcn_mfma_f32_16x16x32_bf16(a1, kb1, acc, 0, 0, 0);
#pragma unroll
        for (int j = 0; j < 4; ++j)
            lds[(4 * lg + j) * 1024 + m0 + lr] += acc[j];  // C/D: col=lane&15, row=4*(l>>4)+j
    }
    __syncthreads();

    // ---- Phase C: row softmax; write P (bf16) aliased over logits[0:32KB) ----
    {
        const int r = tid >> 4, sseg = tid & 15;
        float4 v4[16];
        const float4* rowp = (const float4*)(lds + r * 1024 + sseg * 64);
#pragma unroll
        for (int i = 0; i < 16; ++i) v4[i] = rowp[i];
        __syncthreads();   // everyone finished reading logits before alias overwrite
        float mx = v4[0].x;
#pragma unroll
        for (int i = 0; i < 16; ++i)
            mx = fmaxf(mx, fmaxf(fmaxf(v4[i].x, v4[i].y), fmaxf(v4[i].z, v4[i].w)));
#pragma unroll
        for (int off = 8; off >= 1; off >>= 1) mx = fmaxf(mx, __shfl_xor(mx, off));
        float sum = 0.f;
#pragma unroll
        for (int i = 0; i < 16; ++i) {
            v4[i].x = __expf(v4[i].x - mx); sum += v4[i].x;
            v4[i].y = __expf(v4[i].y - mx); sum += v4[i].y;
            v4[i].z = __expf(v4[i].z - mx); sum += v4[i].z;
            v4[i].w = __expf(v4[i].w - mx); sum += v4[i].w;
        }
#pragma unroll
        for (int off = 8; off >= 1; off >>= 1) sum += __shfl_xor(sum, off);
        float inv = 1.0f / sum;
        ushort_t* pb = ((ushort_t*)lds) + r * 1024 + sseg * 64;
#pragma unroll
        for (int i = 0; i < 8; ++i) {
            uint_t w0 = (uint_t)f2bf(v4[2*i].x * inv)   | ((uint_t)f2bf(v4[2*i].y * inv)   << 16);
            uint_t w1 = (uint_t)f2bf(v4[2*i].z * inv)   | ((uint_t)f2bf(v4[2*i].w * inv)   << 16);
            uint_t w2 = (uint_t)f2bf(v4[2*i+1].x * inv) | ((uint_t)f2bf(v4[2*i+1].y * inv) << 16);
            uint_t w3 = (uint_t)f2bf(v4[2*i+1].z * inv) | ((uint_t)f2bf(v4[2*i+1].w * inv) << 16);
            ((uint4*)pb)[i] = make_uint4(w0, w1, w2, w3);
        }
    }
    __syncthreads();

    // ---- Phase D: out = P V  (V transposed -> contiguous B-frag loads) ----
    {
        f32x4 o[4] = {{0,0,0,0},{0,0,0,0},{0,0,0,0},{0,0,0,0}};
        const ushort_t* __restrict__ pb = ((const ushort_t*)lds) + lr * 1024;
        const ushort_t* __restrict__ Vb = Vt + ((size_t)b << 16);
#pragma unroll 2
        for (int c = 0; c < 8; ++c) {
            int m0 = (wv << 8) + (c << 5) + 8 * lg;
            short8 pa = *(const short8*)(pb + m0);
#pragma unroll
            for (int dt = 0; dt < 4; ++dt) {
                short8 vb = *(const short8*)(Vb + (size_t)(dt * 16 + lr) * 1024 + m0);
                o[dt] = __builtin_amdgcn_mfma_f32_16x16x32_bf16(pa, vb, o[dt], 0, 0, 0);
            }
        }
        float* lo = lds + 8192 + (wv << 10);   // scratch aliases consumed logits
#pragma unroll
        for (int dt = 0; dt < 4; ++dt)
#pragma unroll
            for (int j = 0; j < 4; ++j)
                lo[(4 * lg + j) * 64 + dt * 16 + lr] = o[dt][j];
    }
    __syncthreads();

    // ---- cross-wave reduce + coalesced store ----
#pragma unroll
    for (int i = 0; i < 4; ++i) {
        int idx = (i << 8) + tid;   // r*64 + d
        float s2 = lds[8192 + idx] + lds[8192 + 1024 + idx]
                 + lds[8192 + 2048 + idx] + lds[8192 + 3072 + idx];
        out[((size_t)bn0 << 6) + idx] = s2;
    }
}

extern "C" void kernel_launch(void* const* d_in, const int* in_sizes, int n_in,
                              void* d_out, int out_size, void* d_ws, size_t ws_size,
                              hipStream_t stream) {
    const float* x   = (const float*)d_in[0];
    const float* top = (const float*)d_in[1];
    const float* Wq  = (const float*)d_in[2];
    const float* bq  = (const float*)d_in[3];
    const float* Wk  = (const float*)d_in[4];
    const float* bk  = (const float*)d_in[5];
    const float* Wv  = (const float*)d_in[6];
    const float* bv  = (const float*)d_in[7];
    const float* Wt  = (const float*)d_in[8];
    // d_in[9] = bt: constant added to every logit -> softmax-invariant, dropped.
    float* out = (float*)d_out;

    ushort_t* Q  = (ushort_t*)d_ws;          // [8][1024][64] bf16 (pre-scaled 1/8)
    ushort_t* K  = Q + 8 * 1024 * 64;        // [8][1024][64] bf16
    ushort_t* Vt = K + 8 * 1024 * 64;        // [8][64][1024] bf16 (transposed)

    qkv_all<<<512, 256, 0, stream>>>(x, Wq, bq, Wk, bk, Wv, bv, Q, K, Vt);
    topo_attn_f<<<512, 256, 0, stream>>>(top, Wt, Q, K, Vt, out);
}